// Round 11
// baseline (1680.455 us; speedup 1.0000x reference)
//
#include <hip/hip_runtime.h>

// Sizes (fixed by the problem)
#define TT 256
#define BB 32
#define EE 512
#define HH 256
#define GG 1024   // 4*H
#define NK 17

typedef __attribute__((ext_vector_type(8))) short bf16x8;
typedef __attribute__((ext_vector_type(4))) float f32x4;

__device__ __forceinline__ int dot4i8(int a, int b, int c) {
#if __has_builtin(__builtin_amdgcn_sdot4)
  return __builtin_amdgcn_sdot4(a, b, c, false);
#else
  int r = c;
#pragma unroll
  for (int e = 0; e < 4; ++e) {
    int av = (a << (24 - 8 * e)) >> 24;
    int bv = (b << (24 - 8 * e)) >> 24;
    r += av * bv;
  }
  return r;
#endif
}

__device__ __forceinline__ short f2bf(float f) {
  unsigned int u = __float_as_uint(f);
  unsigned int rounding = 0x7FFFu + ((u >> 16) & 1u);
  return (short)((u + rounding) >> 16);
}
__device__ __forceinline__ float bfu2f_lo(unsigned int u) {
  return __uint_as_float(u << 16);
}
__device__ __forceinline__ float bfu2f_hi(unsigned int u) {
  return __uint_as_float(u & 0xFFFF0000u);
}

// ------------------------------------------------- embedding -> bf16 features
__global__ void k_embed(const int* __restrict__ src,
                        const float* __restrict__ emb,
                        short* __restrict__ xb) {
  int row = blockIdx.x;                 // b*T + t, 8192 rows
  int v = src[row];                     // emb[0] is all-zero, so padding is fine
  int t = threadIdx.x;                  // 64 threads, 8 elems each
  const float4* e = reinterpret_cast<const float4*>(emb + (size_t)v * EE) + 2 * t;
  float4 a = e[0], b = e[1];
  bf16x8 r;
  r[0] = f2bf(a.x); r[1] = f2bf(a.y); r[2] = f2bf(a.z); r[3] = f2bf(a.w);
  r[4] = f2bf(b.x); r[5] = f2bf(b.y); r[6] = f2bf(b.z); r[7] = f2bf(b.w);
  *reinterpret_cast<bf16x8*>(xb + (size_t)row * EE + 8 * t) = r;
}

// ---------------------------------------------------------------- f32 -> bf16
__global__ __launch_bounds__(256) void k_cvt(const float* __restrict__ in,
                                             short* __restrict__ out) {
  int i = (blockIdx.x * 256 + threadIdx.x) * 8;
  float4 a = *reinterpret_cast<const float4*>(in + i);
  float4 b = *reinterpret_cast<const float4*>(in + i + 4);
  bf16x8 r;
  r[0] = f2bf(a.x); r[1] = f2bf(a.y); r[2] = f2bf(a.z); r[3] = f2bf(a.w);
  r[4] = f2bf(b.x); r[5] = f2bf(b.y); r[6] = f2bf(b.z); r[7] = f2bf(b.w);
  *reinterpret_cast<bf16x8*>(out + i) = r;
}

// --------------------------- Whh -> int4, all-gates-per-lane layout
// k_rec lane j (0..255) owns gates i,f,g,o of h-col j. Chunk c = gate*8+qq
// (qq=0..7) is a uint4 = dwords kk=4qq..4qq+3 (K = 32qq..32qq+31).
// Storage (per ld): uint4 index (c*256 + j). Coalesced: lanes j consecutive.
__global__ __launch_bounds__(256) void k_quant4(const float* __restrict__ whh,
                                                int* __restrict__ wq4,
                                                float* __restrict__ scl) {
  int wid = (blockIdx.x * 256 + threadIdx.x) >> 6;  // row id 0..4095 = ld*1024+g
  int lane = threadIdx.x & 63;
  int ld = wid >> 10, g = wid & 1023;
  int gate = g >> 8, j = g & 255;
  float4 v = *reinterpret_cast<const float4*>(whh + (size_t)wid * HH + lane * 4);
  float m = fmaxf(fmaxf(fabsf(v.x), fabsf(v.y)), fmaxf(fabsf(v.z), fabsf(v.w)));
#pragma unroll
  for (int off = 32; off > 0; off >>= 1) m = fmaxf(m, __shfl_xor(m, off));
  m = fmaxf(m, 1e-20f);
  float inv = 7.f / m;
  unsigned q0 = (unsigned)((int)rintf(v.x * inv) & 0xF);
  unsigned q1 = (unsigned)((int)rintf(v.y * inv) & 0xF);
  unsigned q2 = (unsigned)((int)rintf(v.z * inv) & 0xF);
  unsigned q3 = (unsigned)((int)rintf(v.w * inv) & 0xF);
  unsigned bits = q0 | (q1 << 4) | (q2 << 8) | (q3 << 12);   // K = 4*lane + e
  unsigned hi = __shfl_down(bits, 1);
  if (!(lane & 1)) {
    int kk = lane >> 1;                 // dword index, K = 8kk..8kk+7
    wq4[(size_t)ld * 32768 +
        (((gate * 8 + (kk >> 2)) * 256 + j) << 2) + (kk & 3)] =
        (int)(bits | (hi << 16));
  }
  if (lane == 0) scl[wid] = m / (7.f * 16.f * 127.f);
}

__global__ void k_prep_bias(const float* __restrict__ bih,
                            const float* __restrict__ bhh,
                            float* __restrict__ bias) {
  int i = blockIdx.x * 256 + threadIdx.x;     // < 4096
  bias[i] = bih[i] + bhh[i];
}

// ------------------------------------------------- bf16 MFMA xg GEMM (merged dirs)
__global__ __launch_bounds__(256) void k_gemm_mfma(
    const short* __restrict__ Xb,   // [8192][512] bf16
    const short* __restrict__ Wb,   // [2048][512] bf16 (this layer, both dirs)
    const float* __restrict__ bias, // [2048]
    float* __restrict__ out) {      // [2][8192][1024] f32
  __shared__ short As[128][40];     // +8 pad
  __shared__ short Bs[128][40];
  const int tid = threadIdx.x;
  const int wave = tid >> 6, lane = tid & 63;
  const int wr = wave >> 1, wc = wave & 1;
  const int m0 = blockIdx.y * 128, n0 = blockIdx.x * 128;
  f32x4 acc[4][4] = {};             // [mi][ni]
  const int cid0 = tid * 2;
  for (int k0 = 0; k0 < EE; k0 += 32) {
#pragma unroll
    for (int u = 0; u < 2; ++u) {
      int cid = cid0 + u;
      int row = cid >> 2, kc = cid & 3;
      *reinterpret_cast<int4*>(&As[row][kc * 8]) =
          *reinterpret_cast<const int4*>(Xb + (size_t)(m0 + row) * EE + k0 + kc * 8);
      *reinterpret_cast<int4*>(&Bs[row][kc * 8]) =
          *reinterpret_cast<const int4*>(Wb + (size_t)(n0 + row) * EE + k0 + kc * 8);
    }
    __syncthreads();
    bf16x8 af[4], bff[4];
#pragma unroll
    for (int mi = 0; mi < 4; ++mi)
      af[mi] = *reinterpret_cast<const bf16x8*>(&As[wr * 64 + mi * 16 + (lane & 15)][(lane >> 4) * 8]);
#pragma unroll
    for (int ni = 0; ni < 4; ++ni)
      bff[ni] = *reinterpret_cast<const bf16x8*>(&Bs[wc * 64 + ni * 16 + (lane & 15)][(lane >> 4) * 8]);
#pragma unroll
    for (int mi = 0; mi < 4; ++mi)
#pragma unroll
      for (int ni = 0; ni < 4; ++ni)
        acc[mi][ni] = __builtin_amdgcn_mfma_f32_16x16x32_bf16(af[mi], bff[ni], acc[mi][ni], 0, 0, 0);
    __syncthreads();
  }
  const int r0 = (lane >> 4) * 4, cc = lane & 15;
#pragma unroll
  for (int mi = 0; mi < 4; ++mi)
#pragma unroll
    for (int ni = 0; ni < 4; ++ni) {
      int gcol = n0 + wc * 64 + ni * 16 + cc;      // 0..2047
      int dir = gcol >> 10, gg = gcol & 1023;
      float bv = bias[gcol];
      float* ob = out + (size_t)dir * (BB * TT * GG) + gg;
#pragma unroll
      for (int j = 0; j < 4; ++j) {
        int m = m0 + wr * 64 + mi * 16 + r0 + j;
        ob[(size_t)m * GG] = acc[mi][ni][j] + bv;
      }
    }
}

// ------------------------------------------------------------- LSTM recurrence
// One block per (b,dir); 256 threads; lane j owns ALL FOUR gates of h-col j.
// No gate exchange at all; ONE barrier/step; h int8 ping-pong (2x256B LDS).
// int4 weights streamed from L2: 32 coalesced b128/lane/step.
__global__ __launch_bounds__(256) void k_rec(
    const float* __restrict__ xg,        // [2][8192][1024] dir-major, bias included
    const uint4* __restrict__ wq4,       // this layer: [2][32][256] uint4 chunks
    const float* __restrict__ scl,       // this layer: [2][1024]
    const int* __restrict__ lens,        // [32]
    short* __restrict__ outx)            // [8192][512] bf16: [:256]=fwd, [256:]=bwd
{
  __shared__ __align__(16) int hbuf[2][64];  // [ping][0..31 evenK | 32..63 oddK]
  const int bid = blockIdx.x;            // 0..63
  const int b = bid & 31;
  const int dir = bid >> 5;
  const int j = threadIdx.x;             // h-col 0..255
  const uint4* wp = wq4 + (size_t)dir * 8192 + j;
  if (j < 64) { hbuf[0][j] = 0; hbuf[1][j] = 0; }
  const float f0 = scl[dir * 1024 + j];
  const float f1 = scl[dir * 1024 + 256 + j];
  const float f2s = scl[dir * 1024 + 512 + j];
  const float f3 = scl[dir * 1024 + 768 + j];
  const int len = lens[b];
  const float* xgb = xg + ((size_t)dir * (BB * TT) + (size_t)b * TT) * GG + j;
  float c = 0.f, hcur = 0.f;
  __syncthreads();
  const int tfirst = dir ? (TT - 1) : 0;
  float xv0 = xgb[(size_t)tfirst * GG];
  float xv1 = xgb[(size_t)tfirst * GG + 256];
  float xv2 = xgb[(size_t)tfirst * GG + 512];
  float xv3 = xgb[(size_t)tfirst * GG + 768];
  for (int s = 0; s < TT; ++s) {
    const int t = dir ? (TT - 1 - s) : s;
    const int tn = dir ? (TT - 2 - s) : (s + 1);
    float nx0 = 0.f, nx1 = 0.f, nx2 = 0.f, nx3 = 0.f;
    if (s + 1 < TT) {                    // prefetch next step's xv
      nx0 = xgb[(size_t)tn * GG];
      nx1 = xgb[(size_t)tn * GG + 256];
      nx2 = xgb[(size_t)tn * GG + 512];
      nx3 = xgb[(size_t)tn * GG + 768];
    }
    const int p = s & 1;
    const uint4* a4 = reinterpret_cast<const uint4*>(&hbuf[p][0]);
    const uint4* b4 = reinterpret_cast<const uint4*>(&hbuf[p][32]);
    int A0 = 0, A1 = 0, A2 = 0, A3 = 0;
#pragma unroll
    for (int qq = 0; qq < 8; ++qq) {
      uint4 ha = a4[qq], hb = b4[qq];    // uniform addr -> LDS broadcast
#define DOT_GATE(ACC, GATE)                                                   \
      { uint4 wv = wp[((GATE) * 8 + qq) * 256];                               \
        ACC = dot4i8((int)(wv.x << 4) & (int)0xF0F0F0F0, (int)ha.x, ACC);     \
        ACC = dot4i8((int)wv.x & (int)0xF0F0F0F0, (int)hb.x, ACC);            \
        ACC = dot4i8((int)(wv.y << 4) & (int)0xF0F0F0F0, (int)ha.y, ACC);     \
        ACC = dot4i8((int)wv.y & (int)0xF0F0F0F0, (int)hb.y, ACC);            \
        ACC = dot4i8((int)(wv.z << 4) & (int)0xF0F0F0F0, (int)ha.z, ACC);     \
        ACC = dot4i8((int)wv.z & (int)0xF0F0F0F0, (int)hb.z, ACC);            \
        ACC = dot4i8((int)(wv.w << 4) & (int)0xF0F0F0F0, (int)ha.w, ACC);     \
        ACC = dot4i8((int)wv.w & (int)0xF0F0F0F0, (int)hb.w, ACC); }
      DOT_GATE(A0, 0)
      DOT_GATE(A1, 1)
      DOT_GATE(A2, 2)
      DOT_GATE(A3, 3)
#undef DOT_GATE
    }
    float gi = xv0 + (float)A0 * f0;
    float gf = xv1 + (float)A1 * f1;
    float gg = xv2 + (float)A2 * f2s;
    float go = xv3 + (float)A3 * f3;
    float iv = 1.f / (1.f + __expf(-gi));
    float fv = 1.f / (1.f + __expf(-gf));
    float e2 = __expf(fminf(2.f * gg, 80.f));
    float gv = (e2 - 1.f) / (e2 + 1.f);
    float ov = 1.f / (1.f + __expf(-go));
    float cn = fv * c + iv * gv;
    float e2c = __expf(fminf(2.f * cn, 80.f));
    float th = (e2c - 1.f) / (e2c + 1.f);
    float hn = ov * th;
    const bool m = (t < len);
    if (m) { c = cn; hcur = hn; }
    outx[((size_t)(b * TT) + t) * (2 * HH) + dir * HH + j] = f2bf(m ? hn : 0.f);
    // write current h (new or carried) into next ping buffer
    reinterpret_cast<char*>(&hbuf[p ^ 1][0])[((j & 1) << 7) + (j >> 1)] =
        (char)(int)rintf(hcur * 127.f);
    __syncthreads();                     // single barrier: hbuf[p^1] ready
    xv0 = nx0; xv1 = nx1; xv2 = nx2; xv3 = nx3;
  }
}

// ------------------------------------------------------------- logits (bf16 feats)
__global__ __launch_bounds__(256) void k_logits(
    const short* __restrict__ feats,  // [8192][512] bf16
    const float* __restrict__ wlin,   // [17][512] f32
    const float* __restrict__ blin,   // [17]
    float* __restrict__ logits) {     // [8192][17]
  int o = blockIdx.x * 256 + threadIdx.x;      // < 8192*17 = 139264 exactly
  int m = o / NK, jj = o - m * NK;
  const uint4* fr = reinterpret_cast<const uint4*>(feats + (size_t)m * EE);
  const float4* wr = reinterpret_cast<const float4*>(wlin + (size_t)jj * EE);
  float s = blin[jj];
  for (int q = 0; q < EE / 8; ++q) {
    uint4 fv = fr[q];
    float4 w0 = wr[2 * q], w1 = wr[2 * q + 1];
    s = fmaf(bfu2f_lo(fv.x), w0.x, s);
    s = fmaf(bfu2f_hi(fv.x), w0.y, s);
    s = fmaf(bfu2f_lo(fv.y), w0.z, s);
    s = fmaf(bfu2f_hi(fv.y), w0.w, s);
    s = fmaf(bfu2f_lo(fv.z), w1.x, s);
    s = fmaf(bfu2f_hi(fv.z), w1.y, s);
    s = fmaf(bfu2f_lo(fv.w), w1.z, s);
    s = fmaf(bfu2f_hi(fv.w), w1.w, s);
  }
  logits[o] = s;
}

// ------------------------------------------------------------- CRF NLL per batch
// Single wave per batch -> wave-lockstep, no __syncthreads needed.
__global__ __launch_bounds__(64) void k_crf(
    const float* __restrict__ logits,   // [32][256][17]
    const int* __restrict__ labels,     // [32][256]
    const int* __restrict__ lens,       // [32]
    const float* __restrict__ trans,    // [17][17]
    const float* __restrict__ startv,   // [17]
    const float* __restrict__ endv,     // [17]
    float* __restrict__ res) {          // [32] = numerator - partition
  const int b = blockIdx.x;
  const int tid = threadIdx.x;          // one wave
  __shared__ float trs[NK * NK];
  __shared__ float alpha[NK];
  for (int i = tid; i < NK * NK; i += 64) trs[i] = trans[i];
  const int len = lens[b];
  const int* lab = labels + b * TT;
  const float* lg = logits + (size_t)b * TT * NK;
  float part = 0.f;
  for (int t = tid; t < TT; t += 64)
    if (t < len) part += lg[t * NK + lab[t]];
  for (int t = tid; t < TT - 1; t += 64)
    if (t + 1 < len) part += trs[lab[t] * NK + lab[t + 1]];
#pragma unroll
  for (int off = 32; off > 0; off >>= 1) part += __shfl_down(part, off);
  if (tid < NK) alpha[tid] = startv[tid] + lg[tid];
  const int tmax = (len < TT) ? len : TT;
  for (int t = 1; t < tmax; ++t) {
    float nv = 0.f;
    if (tid < NK) {
      float mxv = -1e30f;
#pragma unroll
      for (int i = 0; i < NK; ++i) mxv = fmaxf(mxv, alpha[i] + trs[i * NK + tid]);
      float sum = 0.f;
#pragma unroll
      for (int i = 0; i < NK; ++i) sum += __expf(alpha[i] + trs[i * NK + tid] - mxv);
      nv = mxv + __logf(sum) + lg[t * NK + tid];
    }
    if (tid < NK) alpha[tid] = nv;      // wave-lockstep
  }
  if (tid == 0) {
    float mxv = -1e30f;
    float av[NK];
    for (int i = 0; i < NK; ++i) { av[i] = alpha[i] + endv[i]; mxv = fmaxf(mxv, av[i]); }
    float sum = 0.f;
    for (int i = 0; i < NK; ++i) sum += __expf(av[i] - mxv);
    float partition = mxv + __logf(sum);
    float numer = startv[lab[0]] + part + endv[lab[len - 1]];
    res[b] = numer - partition;
  }
}

__global__ void k_final(const float* __restrict__ res, float* __restrict__ out) {
  int tid = threadIdx.x;  // 64
  float v = (tid < BB) ? res[tid] : 0.f;
#pragma unroll
  for (int off = 32; off > 0; off >>= 1) v += __shfl_down(v, off);
  if (tid == 0) out[0] = -v;
}

extern "C" void kernel_launch(void* const* d_in, const int* in_sizes, int n_in,
                              void* d_out, int out_size, void* d_ws, size_t ws_size,
                              hipStream_t stream) {
  const int* src = (const int*)d_in[0];
  const int* lens = (const int*)d_in[1];
  const int* labels = (const int*)d_in[2];
  // d_in[3] = decode (always 0, ignored)
  const float* emb = (const float*)d_in[4];
  const float* Wih = (const float*)d_in[5];
  const float* Whh = (const float*)d_in[6];
  const float* bih = (const float*)d_in[7];
  const float* bhh = (const float*)d_in[8];
  const float* Wlin = (const float*)d_in[9];
  const float* blin = (const float*)d_in[10];
  const float* trans = (const float*)d_in[11];
  const float* startv = (const float*)d_in[12];
  const float* endv = (const float*)d_in[13];

  char* w = (char*)d_ws;
  short* xb0 = (short*)w;   w += (size_t)BB * TT * EE * 2;        // 8.4 MB
  short* xb1 = (short*)w;   w += (size_t)BB * TT * EE * 2;        // 8.4 MB
  short* xb2 = (short*)w;   w += (size_t)BB * TT * EE * 2;        // 8.4 MB
  float* xg = (float*)w;    w += (size_t)2 * BB * TT * GG * 4;    // 67.1 MB
  int* wq4 = (int*)w;       w += (size_t)4 * 32768 * 4;           // 512 KB
  float* scl = (float*)w;   w += (size_t)4 * 1024 * 4;            // 16 KB
  float* biasb = (float*)w; w += (size_t)2 * 2 * GG * 4;          // 16 KB
  float* logits = (float*)w; w += (size_t)BB * TT * NK * 4;       // 557 KB
  float* res = (float*)w;   w += 256;
  short* wbb = (short*)w;   w += (size_t)4 * GG * EE * 2;         // 4.2 MB

  k_embed<<<BB * TT, 64, 0, stream>>>(src, emb, xb0);
  k_quant4<<<1024, 256, 0, stream>>>(Whh, wq4, scl);
  k_prep_bias<<<16, 256, 0, stream>>>(bih, bhh, biasb);
  k_cvt<<<(4 * GG * EE) / (256 * 8), 256, 0, stream>>>(Wih, wbb);

  const short* xin[2] = {xb0, xb1};
  short* xout[2] = {xb1, xb2};
  for (int l = 0; l < 2; ++l) {
    k_gemm_mfma<<<dim3(2 * GG / 128, (BB * TT) / 128), 256, 0, stream>>>(
        xin[l], wbb + (size_t)l * 2 * GG * EE, biasb + l * 2 * GG, xg);
    k_rec<<<64, 256, 0, stream>>>(
        xg, reinterpret_cast<const uint4*>(wq4) + (size_t)l * 2 * 8192,
        scl + (size_t)l * 2 * 1024, lens, xout[l]);
  }

  k_logits<<<(BB * TT * NK) / 256, 256, 0, stream>>>(xb2, Wlin, blin, logits);
  k_crf<<<BB, 64, 0, stream>>>(logits, labels, lens, trans, startv, endv, res);
  k_final<<<1, 64, 0, stream>>>(res, (float*)d_out);
}

// Round 12
// 720.963 us; speedup vs baseline: 2.3308x; 2.3308x over previous
//
#include <hip/hip_runtime.h>

// Sizes (fixed by the problem)
#define TT 256
#define BB 32
#define EE 512
#define HH 256
#define GG 1024   // 4*H
#define NK 17

typedef __attribute__((ext_vector_type(8))) short bf16x8;
typedef __attribute__((ext_vector_type(4))) float f32x4;

__device__ __forceinline__ int dot4i8(int a, int b, int c) {
#if __has_builtin(__builtin_amdgcn_sdot4)
  return __builtin_amdgcn_sdot4(a, b, c, false);
#else
  int r = c;
#pragma unroll
  for (int e = 0; e < 4; ++e) {
    int av = (a << (24 - 8 * e)) >> 24;
    int bv = (b << (24 - 8 * e)) >> 24;
    r += av * bv;
  }
  return r;
#endif
}

__device__ __forceinline__ short f2bf(float f) {
  unsigned int u = __float_as_uint(f);
  unsigned int rounding = 0x7FFFu + ((u >> 16) & 1u);
  return (short)((u + rounding) >> 16);
}
__device__ __forceinline__ float bfu2f_lo(unsigned int u) {
  return __uint_as_float(u << 16);
}
__device__ __forceinline__ float bfu2f_hi(unsigned int u) {
  return __uint_as_float(u & 0xFFFF0000u);
}
__device__ __forceinline__ float bfs2f(unsigned short us) {
  return __uint_as_float(((unsigned int)us) << 16);
}

// ------------------------------------------------- embedding -> bf16 features
__global__ void k_embed(const int* __restrict__ src,
                        const float* __restrict__ emb,
                        short* __restrict__ xb) {
  int row = blockIdx.x;                 // b*T + t, 8192 rows
  int v = src[row];                     // emb[0] is all-zero, so padding is fine
  int t = threadIdx.x;                  // 64 threads, 8 elems each
  const float4* e = reinterpret_cast<const float4*>(emb + (size_t)v * EE) + 2 * t;
  float4 a = e[0], b = e[1];
  bf16x8 r;
  r[0] = f2bf(a.x); r[1] = f2bf(a.y); r[2] = f2bf(a.z); r[3] = f2bf(a.w);
  r[4] = f2bf(b.x); r[5] = f2bf(b.y); r[6] = f2bf(b.z); r[7] = f2bf(b.w);
  *reinterpret_cast<bf16x8*>(xb + (size_t)row * EE + 8 * t) = r;
}

// ---------------------------------------------------------------- f32 -> bf16
__global__ __launch_bounds__(256) void k_cvt(const float* __restrict__ in,
                                             short* __restrict__ out) {
  int i = (blockIdx.x * 256 + threadIdx.x) * 8;
  float4 a = *reinterpret_cast<const float4*>(in + i);
  float4 b = *reinterpret_cast<const float4*>(in + i + 4);
  bf16x8 r;
  r[0] = f2bf(a.x); r[1] = f2bf(a.y); r[2] = f2bf(a.z); r[3] = f2bf(a.w);
  r[4] = f2bf(b.x); r[5] = f2bf(b.y); r[6] = f2bf(b.z); r[7] = f2bf(b.w);
  *reinterpret_cast<bf16x8*>(out + i) = r;
}

// --------------------------- Whh -> int4 with per-gate-row scale (+ bias prep)
// One wave per row (ld,g). wq4 dword ((ld*8 + kk>>2)*1024 + g)*4 + (kk&3)
// holds K-nibbles for K = 8kk..8kk+7.  (b128-streaming layout, r9-proven)
__global__ __launch_bounds__(256) void k_quant4(const float* __restrict__ whh,
                                                const float* __restrict__ bih,
                                                const float* __restrict__ bhh,
                                                int* __restrict__ wq4,
                                                float* __restrict__ scl,
                                                float* __restrict__ biasb) {
  int wid = (blockIdx.x * 256 + threadIdx.x) >> 6;  // row id 0..4095 = ld*1024+g
  int lane = threadIdx.x & 63;
  int ld = wid >> 10, g = wid & 1023;
  float4 v = *reinterpret_cast<const float4*>(whh + (size_t)wid * HH + lane * 4);
  float m = fmaxf(fmaxf(fabsf(v.x), fabsf(v.y)), fmaxf(fabsf(v.z), fabsf(v.w)));
#pragma unroll
  for (int off = 32; off > 0; off >>= 1) m = fmaxf(m, __shfl_xor(m, off));
  m = fmaxf(m, 1e-20f);
  float inv = 7.f / m;
  unsigned q0 = (unsigned)((int)rintf(v.x * inv) & 0xF);
  unsigned q1 = (unsigned)((int)rintf(v.y * inv) & 0xF);
  unsigned q2 = (unsigned)((int)rintf(v.z * inv) & 0xF);
  unsigned q3 = (unsigned)((int)rintf(v.w * inv) & 0xF);
  unsigned bits = q0 | (q1 << 4) | (q2 << 8) | (q3 << 12);   // K = 4*lane + e
  unsigned hi = __shfl_down(bits, 1);
  if (!(lane & 1)) {
    int kk = lane >> 1;                 // dword index, K = 8kk..8kk+7
    wq4[(((size_t)ld * 8 + (kk >> 2)) * 1024 + g) * 4 + (kk & 3)] =
        (int)(bits | (hi << 16));
  }
  if (lane == 0) scl[wid] = m / (7.f * 16.f * 127.f);
  if (lane == 1) biasb[wid] = bih[wid] + bhh[wid];
}

// ------------------------------------- bf16 MFMA xg GEMM (merged dirs, BK=64)
// out[d][m][g] (bf16) = sum_k X[m][k]*W[d*1024+g][k] + bias[d*1024+g]
// M=8192, N=2048, K=512. 128x128 tile, 4 waves (2x2), wave 64x64 = 4x4 frags.
__global__ __launch_bounds__(256) void k_gemm_mfma(
    const short* __restrict__ Xb,      // [8192][512] bf16
    const short* __restrict__ Wb,      // [2048][512] bf16 (this layer, both dirs)
    const float* __restrict__ bias,    // [2048]
    unsigned short* __restrict__ out) {// [2][8192][1024] bf16
  __shared__ short As[128][72];        // 64 + 8 pad
  __shared__ short Bs[128][72];
  const int tid = threadIdx.x;
  const int wave = tid >> 6, lane = tid & 63;
  const int wr = wave >> 1, wc = wave & 1;
  const int m0 = blockIdx.y * 128, n0 = blockIdx.x * 128;
  f32x4 acc[4][4] = {};                // [mi][ni]
  for (int k0 = 0; k0 < EE; k0 += 64) {
#pragma unroll
    for (int u = 0; u < 4; ++u) {
      int cid = u * 256 + tid;         // 1024 chunks of 8 shorts per matrix
      int row = cid >> 3, kc = cid & 7;
      *reinterpret_cast<int4*>(&As[row][kc * 8]) =
          *reinterpret_cast<const int4*>(Xb + (size_t)(m0 + row) * EE + k0 + kc * 8);
      *reinterpret_cast<int4*>(&Bs[row][kc * 8]) =
          *reinterpret_cast<const int4*>(Wb + (size_t)(n0 + row) * EE + k0 + kc * 8);
    }
    __syncthreads();
#pragma unroll
    for (int ko = 0; ko < 2; ++ko) {
      bf16x8 af[4], bff[4];
#pragma unroll
      for (int mi = 0; mi < 4; ++mi)
        af[mi] = *reinterpret_cast<const bf16x8*>(
            &As[wr * 64 + mi * 16 + (lane & 15)][ko * 32 + (lane >> 4) * 8]);
#pragma unroll
      for (int ni = 0; ni < 4; ++ni)
        bff[ni] = *reinterpret_cast<const bf16x8*>(
            &Bs[wc * 64 + ni * 16 + (lane & 15)][ko * 32 + (lane >> 4) * 8]);
#pragma unroll
      for (int mi = 0; mi < 4; ++mi)
#pragma unroll
        for (int ni = 0; ni < 4; ++ni)
          acc[mi][ni] = __builtin_amdgcn_mfma_f32_16x16x32_bf16(af[mi], bff[ni], acc[mi][ni], 0, 0, 0);
    }
    __syncthreads();
  }
  const int r0 = (lane >> 4) * 4, cc = lane & 15;
#pragma unroll
  for (int mi = 0; mi < 4; ++mi)
#pragma unroll
    for (int ni = 0; ni < 4; ++ni) {
      int gcol = n0 + wc * 64 + ni * 16 + cc;      // 0..2047
      int dir = gcol >> 10, gg = gcol & 1023;
      float bv = bias[gcol];
      unsigned short* ob = out + (size_t)dir * (BB * TT * GG) + gg;
#pragma unroll
      for (int j = 0; j < 4; ++j) {
        int m = m0 + wr * 64 + mi * 16 + r0 + j;
        ob[(size_t)m * GG] = (unsigned short)f2bf(acc[mi][ni][j] + bv);
      }
    }
}

// ------------------------------------------------------------- LSTM recurrence
// r9-proven structure: one block per (b,dir); 1024 threads; int4 weights
// streamed from L2 as 8 coalesced b128 loads/lane/step; h int8 in LDS.
// Only change vs r9: xg is bf16 (half the fetch bytes).
__global__ __launch_bounds__(1024) void k_rec(
    const unsigned short* __restrict__ xg, // [2][8192][1024] bf16, bias included
    const uint4* __restrict__ wq4,       // this layer: [2][8][1024] uint4
    const float* __restrict__ scl,       // this layer: [2][1024]
    const int* __restrict__ lens,        // [32]
    short* __restrict__ outx)            // [8192][512] bf16: [:256]=fwd, [256:]=bwd
{
  __shared__ float pre[GG];              // 4 KB
  __shared__ __align__(16) int hA[32];   // h int8, even K
  __shared__ __align__(16) int hB[32];   // h int8, odd K
  const int bid = blockIdx.x;            // 0..63
  const int b = bid & 31;
  const int dir = bid >> 5;
  const int g = threadIdx.x;             // 0..1023 = gate column
  const uint4* wp = wq4 + (size_t)dir * (8 * 1024) + g;
  if (g < 32) { hA[g] = 0; hB[g] = 0; }
  const float f = scl[dir * 1024 + g];
  const int len = lens[b];
  const unsigned short* xgb = xg + ((size_t)dir * (BB * TT) + (size_t)b * TT) * GG + g;
  float c = 0.f;
  __syncthreads();
  for (int s = 0; s < TT; ++s) {
    const int t = dir ? (TT - 1 - s) : s;
    float xv = bfs2f(xgb[(size_t)t * GG]);  // issued early, consumed after dots
    int acc = 0;
    const uint4* a4 = reinterpret_cast<const uint4*>(hA);
    const uint4* b4 = reinterpret_cast<const uint4*>(hB);
#pragma unroll
    for (int q = 0; q < 8; ++q) {
      uint4 wv = wp[q * 1024];           // coalesced: 64 lanes x 16B contiguous
      uint4 ha = a4[q], hb = b4[q];      // uniform addr -> LDS broadcast
      acc = dot4i8((int)(wv.x << 4) & (int)0xF0F0F0F0, (int)ha.x, acc);
      acc = dot4i8((int)wv.x & (int)0xF0F0F0F0, (int)hb.x, acc);
      acc = dot4i8((int)(wv.y << 4) & (int)0xF0F0F0F0, (int)ha.y, acc);
      acc = dot4i8((int)wv.y & (int)0xF0F0F0F0, (int)hb.y, acc);
      acc = dot4i8((int)(wv.z << 4) & (int)0xF0F0F0F0, (int)ha.z, acc);
      acc = dot4i8((int)wv.z & (int)0xF0F0F0F0, (int)hb.z, acc);
      acc = dot4i8((int)(wv.w << 4) & (int)0xF0F0F0F0, (int)ha.w, acc);
      acc = dot4i8((int)wv.w & (int)0xF0F0F0F0, (int)hb.w, acc);
    }
    pre[g] = xv + (float)acc * f;
    __syncthreads();                     // bar1: pre[] complete, h reads done
    if (g < HH) {
      float gi = pre[g], gf = pre[HH + g], g2 = pre[2 * HH + g], go = pre[3 * HH + g];
      float iv = 1.f / (1.f + __expf(-gi));
      float fv = 1.f / (1.f + __expf(-gf));
      float e2 = __expf(fminf(2.f * g2, 80.f));
      float gv = (e2 - 1.f) / (e2 + 1.f);
      float ov = 1.f / (1.f + __expf(-go));
      float cn = fv * c + iv * gv;
      float e2c = __expf(fminf(2.f * cn, 80.f));
      float th = (e2c - 1.f) / (e2c + 1.f);
      float hn = ov * th;
      const bool m = (t < len);
      outx[((size_t)(b * TT) + t) * (2 * HH) + dir * HH + g] = f2bf(m ? hn : 0.f);
      if (m) {
        c = cn;
        char* dst = reinterpret_cast<char*>((g & 1) ? hB : hA);
        dst[g >> 1] = (char)(int)rintf(hn * 127.f);
      }
    }
    __syncthreads();                     // bar2: hA/hB hold h^{s+1}
  }
}

// ------------------------------------------------------------- logits (bf16 feats)
__global__ __launch_bounds__(256) void k_logits(
    const short* __restrict__ feats,  // [8192][512] bf16
    const float* __restrict__ wlin,   // [17][512] f32
    const float* __restrict__ blin,   // [17]
    float* __restrict__ logits) {     // [8192][17]
  int o = blockIdx.x * 256 + threadIdx.x;      // < 8192*17 = 139264 exactly
  int m = o / NK, jj = o - m * NK;
  const uint4* fr = reinterpret_cast<const uint4*>(feats + (size_t)m * EE);
  const float4* wr = reinterpret_cast<const float4*>(wlin + (size_t)jj * EE);
  float s = blin[jj];
  for (int q = 0; q < EE / 8; ++q) {
    uint4 fv = fr[q];
    float4 w0 = wr[2 * q], w1 = wr[2 * q + 1];
    s = fmaf(bfu2f_lo(fv.x), w0.x, s);
    s = fmaf(bfu2f_hi(fv.x), w0.y, s);
    s = fmaf(bfu2f_lo(fv.y), w0.z, s);
    s = fmaf(bfu2f_hi(fv.y), w0.w, s);
    s = fmaf(bfu2f_lo(fv.z), w1.x, s);
    s = fmaf(bfu2f_hi(fv.z), w1.y, s);
    s = fmaf(bfu2f_lo(fv.w), w1.z, s);
    s = fmaf(bfu2f_hi(fv.w), w1.w, s);
  }
  logits[o] = s;
}

// ------------------------------------------------------------- CRF NLL per batch
// Single wave per batch -> wave-lockstep, no __syncthreads needed.
__global__ __launch_bounds__(64) void k_crf(
    const float* __restrict__ logits,   // [32][256][17]
    const int* __restrict__ labels,     // [32][256]
    const int* __restrict__ lens,       // [32]
    const float* __restrict__ trans,    // [17][17]
    const float* __restrict__ startv,   // [17]
    const float* __restrict__ endv,     // [17]
    float* __restrict__ res) {          // [32] = numerator - partition
  const int b = blockIdx.x;
  const int tid = threadIdx.x;          // one wave
  __shared__ float trs[NK * NK];
  __shared__ float alpha[NK];
  for (int i = tid; i < NK * NK; i += 64) trs[i] = trans[i];
  const int len = lens[b];
  const int* lab = labels + b * TT;
  const float* lg = logits + (size_t)b * TT * NK;
  float part = 0.f;
  for (int t = tid; t < TT; t += 64)
    if (t < len) part += lg[t * NK + lab[t]];
  for (int t = tid; t < TT - 1; t += 64)
    if (t + 1 < len) part += trs[lab[t] * NK + lab[t + 1]];
#pragma unroll
  for (int off = 32; off > 0; off >>= 1) part += __shfl_down(part, off);
  if (tid < NK) alpha[tid] = startv[tid] + lg[tid];
  const int tmax = (len < TT) ? len : TT;
  for (int t = 1; t < tmax; ++t) {
    float nv = 0.f;
    if (tid < NK) {
      float mxv = -1e30f;
#pragma unroll
      for (int i = 0; i < NK; ++i) mxv = fmaxf(mxv, alpha[i] + trs[i * NK + tid]);
      float sum = 0.f;
#pragma unroll
      for (int i = 0; i < NK; ++i) sum += __expf(alpha[i] + trs[i * NK + tid] - mxv);
      nv = mxv + __logf(sum) + lg[t * NK + tid];
    }
    if (tid < NK) alpha[tid] = nv;      // wave-lockstep
  }
  if (tid == 0) {
    float mxv = -1e30f;
    float av[NK];
    for (int i = 0; i < NK; ++i) { av[i] = alpha[i] + endv[i]; mxv = fmaxf(mxv, av[i]); }
    float sum = 0.f;
    for (int i = 0; i < NK; ++i) sum += __expf(av[i] - mxv);
    float partition = mxv + __logf(sum);
    float numer = startv[lab[0]] + part + endv[lab[len - 1]];
    res[b] = numer - partition;
  }
}

__global__ void k_final(const float* __restrict__ res, float* __restrict__ out) {
  int tid = threadIdx.x;  // 64
  float v = (tid < BB) ? res[tid] : 0.f;
#pragma unroll
  for (int off = 32; off > 0; off >>= 1) v += __shfl_down(v, off);
  if (tid == 0) out[0] = -v;
}

extern "C" void kernel_launch(void* const* d_in, const int* in_sizes, int n_in,
                              void* d_out, int out_size, void* d_ws, size_t ws_size,
                              hipStream_t stream) {
  const int* src = (const int*)d_in[0];
  const int* lens = (const int*)d_in[1];
  const int* labels = (const int*)d_in[2];
  // d_in[3] = decode (always 0, ignored)
  const float* emb = (const float*)d_in[4];
  const float* Wih = (const float*)d_in[5];
  const float* Whh = (const float*)d_in[6];
  const float* bih = (const float*)d_in[7];
  const float* bhh = (const float*)d_in[8];
  const float* Wlin = (const float*)d_in[9];
  const float* blin = (const float*)d_in[10];
  const float* trans = (const float*)d_in[11];
  const float* startv = (const float*)d_in[12];
  const float* endv = (const float*)d_in[13];

  char* w = (char*)d_ws;
  short* xb0 = (short*)w;   w += (size_t)BB * TT * EE * 2;        // 8.4 MB
  short* xb1 = (short*)w;   w += (size_t)BB * TT * EE * 2;        // 8.4 MB
  short* xb2 = (short*)w;   w += (size_t)BB * TT * EE * 2;        // 8.4 MB
  unsigned short* xg = (unsigned short*)w; w += (size_t)2 * BB * TT * GG * 2; // 33.5 MB
  int* wq4 = (int*)w;       w += (size_t)4 * 32 * 1024 * 4;       // 512 KB
  float* scl = (float*)w;   w += (size_t)4 * 1024 * 4;            // 16 KB
  float* biasb = (float*)w; w += (size_t)2 * 2 * GG * 4;          // 16 KB
  float* logits = (float*)w; w += (size_t)BB * TT * NK * 4;       // 557 KB
  float* res = (float*)w;   w += 256;
  short* wbb = (short*)w;   w += (size_t)4 * GG * EE * 2;         // 4.2 MB

  k_embed<<<BB * TT, 64, 0, stream>>>(src, emb, xb0);
  k_quant4<<<1024, 256, 0, stream>>>(Whh, bih, bhh, wq4, scl, biasb);
  k_cvt<<<(4 * GG * EE) / (256 * 8), 256, 0, stream>>>(Wih, wbb);

  const short* xin[2] = {xb0, xb1};
  short* xout[2] = {xb1, xb2};
  for (int l = 0; l < 2; ++l) {
    k_gemm_mfma<<<dim3(2 * GG / 128, (BB * TT) / 128), 256, 0, stream>>>(
        xin[l], wbb + (size_t)l * 2 * GG * EE, biasb + l * 2 * GG, xg);
    k_rec<<<64, 1024, 0, stream>>>(
        xg, reinterpret_cast<const uint4*>(wq4) + (size_t)l * 2 * 8 * 1024,
        scl + (size_t)l * 2 * 1024, lens, xout[l]);
  }

  k_logits<<<(BB * TT * NK) / 256, 256, 0, stream>>>(xb2, Wlin, blin, logits);
  k_crf<<<BB, 64, 0, stream>>>(logits, labels, lens, trans, startv, endv, res);
  k_final<<<1, 64, 0, stream>>>(res, (float*)d_out);
}

// Round 13
// 597.113 us; speedup vs baseline: 2.8143x; 1.2074x over previous
//
#include <hip/hip_runtime.h>

// Sizes (fixed by the problem)
#define TT 256
#define BB 32
#define EE 512
#define HH 256
#define GG 1024   // 4*H
#define NK 17

typedef __attribute__((ext_vector_type(8))) short bf16x8;
typedef __attribute__((ext_vector_type(4))) float f32x4;

#if __has_builtin(__builtin_amdgcn_sdot8)
#define HAS_DOT8 1
#else
#define HAS_DOT8 0
#endif

__device__ __forceinline__ int dot4i8(int a, int b, int c) {
#if __has_builtin(__builtin_amdgcn_sdot4)
  return __builtin_amdgcn_sdot4(a, b, c, false);
#else
  int r = c;
#pragma unroll
  for (int e = 0; e < 4; ++e) {
    int av = (a << (24 - 8 * e)) >> 24;
    int bv = (b << (24 - 8 * e)) >> 24;
    r += av * bv;
  }
  return r;
#endif
}

// nibble-dot: sum_i a4[i]*b4[i] + c  (8 signed 4-bit lanes per dword)
__device__ __forceinline__ int dot8i4(int a, int b, int c) {
#if HAS_DOT8
  return __builtin_amdgcn_sdot8(a, b, c, false);
#else
  // unpack both to value*16 bytes; caller divides by 256 via scale
  int alo = (a << 4) & (int)0xF0F0F0F0, ahi = a & (int)0xF0F0F0F0;
  int blo = (b << 4) & (int)0xF0F0F0F0, bhi = b & (int)0xF0F0F0F0;
  c = dot4i8(alo, blo, c);
  return dot4i8(ahi, bhi, c);
#endif
}

__device__ __forceinline__ short f2bf(float f) {
  unsigned int u = __float_as_uint(f);
  unsigned int rounding = 0x7FFFu + ((u >> 16) & 1u);
  return (short)((u + rounding) >> 16);
}
__device__ __forceinline__ float bfu2f_lo(unsigned int u) {
  return __uint_as_float(u << 16);
}
__device__ __forceinline__ float bfu2f_hi(unsigned int u) {
  return __uint_as_float(u & 0xFFFF0000u);
}
__device__ __forceinline__ float bfs2f(unsigned short us) {
  return __uint_as_float(((unsigned int)us) << 16);
}

// ------------------------------------------------- embedding -> bf16 features
__global__ void k_embed(const int* __restrict__ src,
                        const float* __restrict__ emb,
                        short* __restrict__ xb) {
  int row = blockIdx.x;                 // b*T + t, 8192 rows
  int v = src[row];                     // emb[0] is all-zero, so padding is fine
  int t = threadIdx.x;                  // 64 threads, 8 elems each
  const float4* e = reinterpret_cast<const float4*>(emb + (size_t)v * EE) + 2 * t;
  float4 a = e[0], b = e[1];
  bf16x8 r;
  r[0] = f2bf(a.x); r[1] = f2bf(a.y); r[2] = f2bf(a.z); r[3] = f2bf(a.w);
  r[4] = f2bf(b.x); r[5] = f2bf(b.y); r[6] = f2bf(b.z); r[7] = f2bf(b.w);
  *reinterpret_cast<bf16x8*>(xb + (size_t)row * EE + 8 * t) = r;
}

// ---------------------------------------------------------------- f32 -> bf16
__global__ __launch_bounds__(256) void k_cvt(const float* __restrict__ in,
                                             short* __restrict__ out) {
  int i = (blockIdx.x * 256 + threadIdx.x) * 8;
  float4 a = *reinterpret_cast<const float4*>(in + i);
  float4 b = *reinterpret_cast<const float4*>(in + i + 4);
  bf16x8 r;
  r[0] = f2bf(a.x); r[1] = f2bf(a.y); r[2] = f2bf(a.z); r[3] = f2bf(a.w);
  r[4] = f2bf(b.x); r[5] = f2bf(b.y); r[6] = f2bf(b.z); r[7] = f2bf(b.w);
  *reinterpret_cast<bf16x8*>(out + i) = r;
}

// --------------------------- Whh -> int4 with per-gate-row scale (+ bias prep)
// One wave per row (ld,g). wq4 dword ((ld*8 + kk>>2)*1024 + g)*4 + (kk&3)
// holds K-nibbles for K = 8kk..8kk+7 (low nibble first).
// scl = rowmax/49  (w/7 scale x h*7 scale for the nibble-dot)
__global__ __launch_bounds__(256) void k_quant4(const float* __restrict__ whh,
                                                const float* __restrict__ bih,
                                                const float* __restrict__ bhh,
                                                int* __restrict__ wq4,
                                                float* __restrict__ scl,
                                                float* __restrict__ biasb) {
  int wid = (blockIdx.x * 256 + threadIdx.x) >> 6;  // row id 0..4095 = ld*1024+g
  int lane = threadIdx.x & 63;
  int ld = wid >> 10, g = wid & 1023;
  float4 v = *reinterpret_cast<const float4*>(whh + (size_t)wid * HH + lane * 4);
  float m = fmaxf(fmaxf(fabsf(v.x), fabsf(v.y)), fmaxf(fabsf(v.z), fabsf(v.w)));
#pragma unroll
  for (int off = 32; off > 0; off >>= 1) m = fmaxf(m, __shfl_xor(m, off));
  m = fmaxf(m, 1e-20f);
  float inv = 7.f / m;
  unsigned q0 = (unsigned)((int)rintf(v.x * inv) & 0xF);
  unsigned q1 = (unsigned)((int)rintf(v.y * inv) & 0xF);
  unsigned q2 = (unsigned)((int)rintf(v.z * inv) & 0xF);
  unsigned q3 = (unsigned)((int)rintf(v.w * inv) & 0xF);
  unsigned bits = q0 | (q1 << 4) | (q2 << 8) | (q3 << 12);   // K = 4*lane + e
  unsigned hi = __shfl_down(bits, 1);
  if (!(lane & 1)) {
    int kk = lane >> 1;                 // dword index, K = 8kk..8kk+7
    wq4[(((size_t)ld * 8 + (kk >> 2)) * 1024 + g) * 4 + (kk & 3)] =
        (int)(bits | (hi << 16));
  }
  if (lane == 0) scl[wid] = m / 49.f;
  if (lane == 1) biasb[wid] = bih[wid] + bhh[wid];
}

// ------------------------------------- bf16 MFMA xg GEMM (merged dirs, BK=64)
__global__ __launch_bounds__(256) void k_gemm_mfma(
    const short* __restrict__ Xb,      // [8192][512] bf16
    const short* __restrict__ Wb,      // [2048][512] bf16 (this layer, both dirs)
    const float* __restrict__ bias,    // [2048]
    unsigned short* __restrict__ out) {// [2][8192][1024] bf16
  __shared__ short As[128][72];        // 64 + 8 pad
  __shared__ short Bs[128][72];
  const int tid = threadIdx.x;
  const int wave = tid >> 6, lane = tid & 63;
  const int wr = wave >> 1, wc = wave & 1;
  const int m0 = blockIdx.y * 128, n0 = blockIdx.x * 128;
  f32x4 acc[4][4] = {};                // [mi][ni]
  for (int k0 = 0; k0 < EE; k0 += 64) {
#pragma unroll
    for (int u = 0; u < 4; ++u) {
      int cid = u * 256 + tid;         // 1024 chunks of 8 shorts per matrix
      int row = cid >> 3, kc = cid & 7;
      *reinterpret_cast<int4*>(&As[row][kc * 8]) =
          *reinterpret_cast<const int4*>(Xb + (size_t)(m0 + row) * EE + k0 + kc * 8);
      *reinterpret_cast<int4*>(&Bs[row][kc * 8]) =
          *reinterpret_cast<const int4*>(Wb + (size_t)(n0 + row) * EE + k0 + kc * 8);
    }
    __syncthreads();
#pragma unroll
    for (int ko = 0; ko < 2; ++ko) {
      bf16x8 af[4], bff[4];
#pragma unroll
      for (int mi = 0; mi < 4; ++mi)
        af[mi] = *reinterpret_cast<const bf16x8*>(
            &As[wr * 64 + mi * 16 + (lane & 15)][ko * 32 + (lane >> 4) * 8]);
#pragma unroll
      for (int ni = 0; ni < 4; ++ni)
        bff[ni] = *reinterpret_cast<const bf16x8*>(
            &Bs[wc * 64 + ni * 16 + (lane & 15)][ko * 32 + (lane >> 4) * 8]);
#pragma unroll
      for (int mi = 0; mi < 4; ++mi)
#pragma unroll
        for (int ni = 0; ni < 4; ++ni)
          acc[mi][ni] = __builtin_amdgcn_mfma_f32_16x16x32_bf16(af[mi], bff[ni], acc[mi][ni], 0, 0, 0);
    }
    __syncthreads();
  }
  const int r0 = (lane >> 4) * 4, cc = lane & 15;
#pragma unroll
  for (int mi = 0; mi < 4; ++mi)
#pragma unroll
    for (int ni = 0; ni < 4; ++ni) {
      int gcol = n0 + wc * 64 + ni * 16 + cc;      // 0..2047
      int dir = gcol >> 10, gg = gcol & 1023;
      float bv = bias[gcol];
      unsigned short* ob = out + (size_t)dir * (BB * TT * GG) + gg;
#pragma unroll
      for (int j = 0; j < 4; ++j) {
        int m = m0 + wr * 64 + mi * 16 + r0 + j;
        ob[(size_t)m * GG] = (unsigned short)f2bf(acc[mi][ni][j] + bv);
      }
    }
}

// ------------------------------------------------------------- LSTM recurrence
// r9/r12 structure; NEW: h stored as packed int4 nibbles (128B) and the dot
// uses v_dot8_i32_i4 on nibble pairs -> no unpack VALU, half the LDS reads.
__global__ __launch_bounds__(1024) void k_rec(
    const unsigned short* __restrict__ xg, // [2][8192][1024] bf16, bias included
    const uint4* __restrict__ wq4,       // this layer: [2][8][1024] uint4
    const float* __restrict__ scl,       // this layer: [2][1024]  (= wmax/49)
    const int* __restrict__ lens,        // [32]
    short* __restrict__ outx)            // [8192][512] bf16: [:256]=fwd, [256:]=bwd
{
  __shared__ __align__(16) int hq[32];   // 256 h values as int4 nibbles (128 B)
  const int bid = blockIdx.x;            // 0..63
  const int b = bid & 31;
  const int dir = bid >> 5;
  const int g = threadIdx.x;             // 0..1023 = gate column
  const uint4* wp = wq4 + (size_t)dir * (8 * 1024) + g;
  if (g < 32) hq[g] = 0;
#if HAS_DOT8
  const float f = scl[dir * 1024 + g];
#else
  const float f = scl[dir * 1024 + g] * (1.f / 256.f);
#endif
  __shared__ float pre[GG];              // 4 KB
  const int len = lens[b];
  const unsigned short* xgb = xg + ((size_t)dir * (BB * TT) + (size_t)b * TT) * GG + g;
  float c = 0.f;
  __syncthreads();
  for (int s = 0; s < TT; ++s) {
    const int t = dir ? (TT - 1 - s) : s;
    float xv = bfs2f(xgb[(size_t)t * GG]);  // issued early, consumed after dots
    // read all h nibbles up-front (8 uniform b128 -> 32 VGPRs)
    const uint4* h4 = reinterpret_cast<const uint4*>(hq);
    uint4 hv0 = h4[0], hv1 = h4[1], hv2 = h4[2], hv3 = h4[3];
    uint4 hv4 = h4[4], hv5 = h4[5], hv6 = h4[6], hv7 = h4[7];
    int acc = 0;
#define DOTQ(Q, HV)                                \
    { uint4 wv = wp[(Q) * 1024];                   \
      acc = dot8i4((int)wv.x, (int)HV.x, acc);     \
      acc = dot8i4((int)wv.y, (int)HV.y, acc);     \
      acc = dot8i4((int)wv.z, (int)HV.z, acc);     \
      acc = dot8i4((int)wv.w, (int)HV.w, acc); }
    DOTQ(0, hv0) DOTQ(1, hv1) DOTQ(2, hv2) DOTQ(3, hv3)
    DOTQ(4, hv4) DOTQ(5, hv5) DOTQ(6, hv6) DOTQ(7, hv7)
#undef DOTQ
    pre[g] = xv + (float)acc * f;
    __syncthreads();                     // bar1: pre[] complete, hq reads done
    if (g < HH) {
      float gi = pre[g], gf = pre[HH + g], g2 = pre[2 * HH + g], go = pre[3 * HH + g];
      float iv = 1.f / (1.f + __expf(-gi));
      float fv = 1.f / (1.f + __expf(-gf));
      float e2 = __expf(fminf(2.f * g2, 80.f));
      float gv = (e2 - 1.f) / (e2 + 1.f);
      float ov = 1.f / (1.f + __expf(-go));
      float cn = fv * c + iv * gv;
      float e2c = __expf(fminf(2.f * cn, 80.f));
      float th = (e2c - 1.f) / (e2c + 1.f);
      float hn = ov * th;
      const bool m = (t < len);
      outx[((size_t)(b * TT) + t) * (2 * HH) + dir * HH + g] = f2bf(m ? hn : 0.f);
      if (m) {
        c = cn;
        int nib = ((int)rintf(hn * 7.f)) & 0xF;       // h quantized to int4
        int pn = __shfl_xor(nib, 1);                  // partner col g^1
        if (!(g & 1))                                 // even col writes the byte
          reinterpret_cast<char*>(hq)[g >> 1] = (char)(nib | (pn << 4));
      }
    }
    __syncthreads();                     // bar2: hq holds h^{s+1}
  }
}

// ------------------------------------------------------------- logits (bf16 feats)
__global__ __launch_bounds__(256) void k_logits(
    const short* __restrict__ feats,  // [8192][512] bf16
    const float* __restrict__ wlin,   // [17][512] f32
    const float* __restrict__ blin,   // [17]
    float* __restrict__ logits) {     // [8192][17]
  int o = blockIdx.x * 256 + threadIdx.x;      // < 8192*17 = 139264 exactly
  int m = o / NK, jj = o - m * NK;
  const uint4* fr = reinterpret_cast<const uint4*>(feats + (size_t)m * EE);
  const float4* wr = reinterpret_cast<const float4*>(wlin + (size_t)jj * EE);
  float s = blin[jj];
  for (int q = 0; q < EE / 8; ++q) {
    uint4 fv = fr[q];
    float4 w0 = wr[2 * q], w1 = wr[2 * q + 1];
    s = fmaf(bfu2f_lo(fv.x), w0.x, s);
    s = fmaf(bfu2f_hi(fv.x), w0.y, s);
    s = fmaf(bfu2f_lo(fv.y), w0.z, s);
    s = fmaf(bfu2f_hi(fv.y), w0.w, s);
    s = fmaf(bfu2f_lo(fv.z), w1.x, s);
    s = fmaf(bfu2f_hi(fv.z), w1.y, s);
    s = fmaf(bfu2f_lo(fv.w), w1.z, s);
    s = fmaf(bfu2f_hi(fv.w), w1.w, s);
  }
  logits[o] = s;
}

// ------------------------------------------------------------- CRF NLL per batch
// Single wave per batch -> wave-lockstep, no __syncthreads needed.
__global__ __launch_bounds__(64) void k_crf(
    const float* __restrict__ logits,   // [32][256][17]
    const int* __restrict__ labels,     // [32][256]
    const int* __restrict__ lens,       // [32]
    const float* __restrict__ trans,    // [17][17]
    const float* __restrict__ startv,   // [17]
    const float* __restrict__ endv,     // [17]
    float* __restrict__ res) {          // [32] = numerator - partition
  const int b = blockIdx.x;
  const int tid = threadIdx.x;          // one wave
  __shared__ float trs[NK * NK];
  __shared__ float alpha[NK];
  for (int i = tid; i < NK * NK; i += 64) trs[i] = trans[i];
  const int len = lens[b];
  const int* lab = labels + b * TT;
  const float* lg = logits + (size_t)b * TT * NK;
  float part = 0.f;
  for (int t = tid; t < TT; t += 64)
    if (t < len) part += lg[t * NK + lab[t]];
  for (int t = tid; t < TT - 1; t += 64)
    if (t + 1 < len) part += trs[lab[t] * NK + lab[t + 1]];
#pragma unroll
  for (int off = 32; off > 0; off >>= 1) part += __shfl_down(part, off);
  if (tid < NK) alpha[tid] = startv[tid] + lg[tid];
  const int tmax = (len < TT) ? len : TT;
  for (int t = 1; t < tmax; ++t) {
    float nv = 0.f;
    if (tid < NK) {
      float mxv = -1e30f;
#pragma unroll
      for (int i = 0; i < NK; ++i) mxv = fmaxf(mxv, alpha[i] + trs[i * NK + tid]);
      float sum = 0.f;
#pragma unroll
      for (int i = 0; i < NK; ++i) sum += __expf(alpha[i] + trs[i * NK + tid] - mxv);
      nv = mxv + __logf(sum) + lg[t * NK + tid];
    }
    if (tid < NK) alpha[tid] = nv;      // wave-lockstep
  }
  if (tid == 0) {
    float mxv = -1e30f;
    float av[NK];
    for (int i = 0; i < NK; ++i) { av[i] = alpha[i] + endv[i]; mxv = fmaxf(mxv, av[i]); }
    float sum = 0.f;
    for (int i = 0; i < NK; ++i) sum += __expf(av[i] - mxv);
    float partition = mxv + __logf(sum);
    float numer = startv[lab[0]] + part + endv[lab[len - 1]];
    res[b] = numer - partition;
  }
}

__global__ void k_final(const float* __restrict__ res, float* __restrict__ out) {
  int tid = threadIdx.x;  // 64
  float v = (tid < BB) ? res[tid] : 0.f;
#pragma unroll
  for (int off = 32; off > 0; off >>= 1) v += __shfl_down(v, off);
  if (tid == 0) out[0] = -v;
}

extern "C" void kernel_launch(void* const* d_in, const int* in_sizes, int n_in,
                              void* d_out, int out_size, void* d_ws, size_t ws_size,
                              hipStream_t stream) {
  const int* src = (const int*)d_in[0];
  const int* lens = (const int*)d_in[1];
  const int* labels = (const int*)d_in[2];
  // d_in[3] = decode (always 0, ignored)
  const float* emb = (const float*)d_in[4];
  const float* Wih = (const float*)d_in[5];
  const float* Whh = (const float*)d_in[6];
  const float* bih = (const float*)d_in[7];
  const float* bhh = (const float*)d_in[8];
  const float* Wlin = (const float*)d_in[9];
  const float* blin = (const float*)d_in[10];
  const float* trans = (const float*)d_in[11];
  const float* startv = (const float*)d_in[12];
  const float* endv = (const float*)d_in[13];

  char* w = (char*)d_ws;
  short* xb0 = (short*)w;   w += (size_t)BB * TT * EE * 2;        // 8.4 MB
  short* xb1 = (short*)w;   w += (size_t)BB * TT * EE * 2;        // 8.4 MB
  short* xb2 = (short*)w;   w += (size_t)BB * TT * EE * 2;        // 8.4 MB
  unsigned short* xg = (unsigned short*)w; w += (size_t)2 * BB * TT * GG * 2; // 33.5 MB
  int* wq4 = (int*)w;       w += (size_t)4 * 32 * 1024 * 4;       // 512 KB
  float* scl = (float*)w;   w += (size_t)4 * 1024 * 4;            // 16 KB
  float* biasb = (float*)w; w += (size_t)2 * 2 * GG * 4;          // 16 KB
  float* logits = (float*)w; w += (size_t)BB * TT * NK * 4;       // 557 KB
  float* res = (float*)w;   w += 256;
  short* wbb = (short*)w;   w += (size_t)4 * GG * EE * 2;         // 4.2 MB

  k_embed<<<BB * TT, 64, 0, stream>>>(src, emb, xb0);
  k_quant4<<<1024, 256, 0, stream>>>(Whh, bih, bhh, wq4, scl, biasb);
  k_cvt<<<(4 * GG * EE) / (256 * 8), 256, 0, stream>>>(Wih, wbb);

  const short* xin[2] = {xb0, xb1};
  short* xout[2] = {xb1, xb2};
  for (int l = 0; l < 2; ++l) {
    k_gemm_mfma<<<dim3(2 * GG / 128, (BB * TT) / 128), 256, 0, stream>>>(
        xin[l], wbb + (size_t)l * 2 * GG * EE, biasb + l * 2 * GG, xg);
    k_rec<<<64, 1024, 0, stream>>>(
        xg, reinterpret_cast<const uint4*>(wq4) + (size_t)l * 2 * 8 * 1024,
        scl + (size_t)l * 2 * 1024, lens, xout[l]);
  }

  k_logits<<<(BB * TT * NK) / 256, 256, 0, stream>>>(xb2, Wlin, blin, logits);
  k_crf<<<BB, 64, 0, stream>>>(logits, labels, lens, trans, startv, endv, res);
  k_final<<<1, 64, 0, stream>>>(res, (float*)d_out);
}